// Round 8
// baseline (70572.778 us; speedup 1.0000x reference)
//
#include <hip/hip_runtime.h>

#define BB 32
#define TT 150
#define LL 400
#define FEATD 512
#define RNND 512
#define ATTD 512
#define EMBD 256
#define VOCABD 5000
#define G3 1536
#define GRID 256
#define TPB 512
#define NCTR 32

__device__ __forceinline__ float fsigmoid(float x) { return 1.f / (1.f + __expf(-x)); }
__device__ __forceinline__ float ftanh(float x) {
    x = fminf(15.f, fmaxf(-15.f, x));
    float e = __expf(2.f * x);
    return 1.f - 2.f / (e + 1.f);
}
__device__ __forceinline__ void fma4(float4& a, const float4 w, const float s) {
    a.x += w.x * s; a.y += w.y * s; a.z += w.z * s; a.w += w.w * s;
}

// Grid barrier (R3-proven-correct): release fence -> arrive -> spin -> acquire.
// 256 blocks x 512 thr = 1 block/CU guaranteed co-resident (8 waves/CU).
__device__ __forceinline__ void gridbar(unsigned* ctr, int ph) {
    __syncthreads();
    __threadfence();
    if (threadIdx.x == 0)
        atomicAdd(&ctr[blockIdx.x & (NCTR - 1)], 1u);
    if (threadIdx.x < NCTR) {
        unsigned tgt = (unsigned)ph * (GRID / NCTR);
        while (__hip_atomic_load(&ctr[threadIdx.x], __ATOMIC_RELAXED,
                                 __HIP_MEMORY_SCOPE_AGENT) < tgt)
            __builtin_amdgcn_s_sleep(4);
    }
    __threadfence();
    __syncthreads();
}

// ---------------- one-time GEMM: [B*L,512] @ [512,512] (fp and G) ----------------
__global__ void __launch_bounds__(256) k_proj512(const float* __restrict__ features,
                                                 const float* __restrict__ W,
                                                 float* __restrict__ outb) {
    __shared__ float sa[64 * 68];
    int blt = blockIdx.x >> 2, at = blockIdx.x & 3;
    int bl0 = blt * 64;
    int tid = threadIdx.x;
    int aq = tid & 31, blg = tid >> 5;
    float4 acc[8] = {};
    for (int kc = 0; kc < FEATD; kc += 64) {
        __syncthreads();
        for (int it = 0; it < 16; ++it) {
            int lin = it * 256 + tid;
            int k = lin & 63, bl = lin >> 6;
            sa[k * 68 + bl] = features[((size_t)bl0 + bl) * FEATD + kc + k];
        }
        __syncthreads();
#pragma unroll 4
        for (int k = 0; k < 64; ++k) {
            float4 w = *(const float4*)&W[(size_t)(kc + k) * 512 + at * 128 + aq * 4];
            float4 s0 = *(const float4*)&sa[k * 68 + blg * 8];
            float4 s1 = *(const float4*)&sa[k * 68 + blg * 8 + 4];
            fma4(acc[0], w, s0.x); fma4(acc[1], w, s0.y);
            fma4(acc[2], w, s0.z); fma4(acc[3], w, s0.w);
            fma4(acc[4], w, s1.x); fma4(acc[5], w, s1.y);
            fma4(acc[6], w, s1.z); fma4(acc[7], w, s1.w);
        }
    }
#pragma unroll
    for (int i = 0; i < 8; ++i)
        *(float4*)&outb[((size_t)bl0 + blg * 8 + i) * 512 + at * 128 + aq * 4] = acc[i];
}

// ---------------- P1: gates + GRU combine -> h. 64 tasks, 8-wide j-slice ----------------
// Full-K (no partials): thread (b32 x kq16) accumulates k-strided slices of all
// 6 gate dots for 8 j's, shfl-reduce over kq, kq==0 computes h.
__device__ void task_gru(int jt, int t, const float* emb, const int* formula,
                         const float* Wk, const float* Wr, const float* gruB,
                         const float* hin, const float* lo, float* hout,
                         float* sm, int* stok) {
    int tid = threadIdx.x;
    int b = tid >> 4, kq = tid & 15;
    int j0 = jt * 8;
    if (tid < BB) stok[tid] = formula[tid * TT + t];
    float ax[24], ar[24];
#pragma unroll
    for (int i = 0; i < 24; ++i) { ax[i] = 0.f; ar[i] = 0.f; }
    // mx: K=768 in 6 chunks of 128
    for (int c = 0; c < 6; ++c) {
        __syncthreads();
        for (int it = 0; it < 8; ++it) {
            int lin = it * 512 + tid;
            int k = lin & 127, bb2 = lin >> 7;
            int kk = c * 128 + k;
            sm[k * 33 + bb2] = (kk < EMBD) ? emb[(size_t)stok[bb2] * EMBD + kk]
                                           : lo[(size_t)bb2 * RNND + (kk - EMBD)];
        }
        __syncthreads();
#pragma unroll 2
        for (int kk = 0; kk < 8; ++kk) {
            int k = kq * 8 + kk;
            float s = sm[k * 33 + b];
            const float* wr_ = &Wk[(size_t)(c * 128 + k) * G3 + j0];
#pragma unroll
            for (int g = 0; g < 3; ++g) {
                float4 wA = *(const float4*)(wr_ + g * 512);
                float4 wB = *(const float4*)(wr_ + g * 512 + 4);
                ax[g*8+0] += wA.x*s; ax[g*8+1] += wA.y*s;
                ax[g*8+2] += wA.z*s; ax[g*8+3] += wA.w*s;
                ax[g*8+4] += wB.x*s; ax[g*8+5] += wB.y*s;
                ax[g*8+6] += wB.z*s; ax[g*8+7] += wB.w*s;
            }
        }
    }
    // mh: K=512 in 4 chunks
    for (int c = 0; c < 4; ++c) {
        __syncthreads();
        for (int it = 0; it < 8; ++it) {
            int lin = it * 512 + tid;
            int k = lin & 127, bb2 = lin >> 7;
            sm[k * 33 + bb2] = hin[(size_t)bb2 * RNND + c * 128 + k];
        }
        __syncthreads();
#pragma unroll 2
        for (int kk = 0; kk < 8; ++kk) {
            int k = kq * 8 + kk;
            float s = sm[k * 33 + b];
            const float* wr_ = &Wr[(size_t)(c * 128 + k) * G3 + j0];
#pragma unroll
            for (int g = 0; g < 3; ++g) {
                float4 wA = *(const float4*)(wr_ + g * 512);
                float4 wB = *(const float4*)(wr_ + g * 512 + 4);
                ar[g*8+0] += wA.x*s; ar[g*8+1] += wA.y*s;
                ar[g*8+2] += wA.z*s; ar[g*8+3] += wA.w*s;
                ar[g*8+4] += wB.x*s; ar[g*8+5] += wB.y*s;
                ar[g*8+6] += wB.z*s; ar[g*8+7] += wB.w*s;
            }
        }
    }
    // reduce over kq (16 lanes per b, in-wave: tid = b*16+kq)
#pragma unroll
    for (int i = 0; i < 24; ++i) {
#pragma unroll
        for (int o = 1; o < 16; o <<= 1) {
            ax[i] += __shfl_xor(ax[i], o);
            ar[i] += __shfl_xor(ar[i], o);
        }
    }
    if (kq == 0) {
#pragma unroll
        for (int jj = 0; jj < 8; ++jj) {
            int col = j0 + jj;
            float xz = ax[jj]      + gruB[col];
            float xr = ax[8 + jj]  + gruB[512 + col];
            float xh = ax[16 + jj] + gruB[1024 + col];
            float rz = ar[jj]      + gruB[1536 + col];
            float rr = ar[8 + jj]  + gruB[2048 + col];
            float rh = ar[16 + jj] + gruB[2560 + col];
            float z = fsigmoid(xz + rz), r = fsigmoid(xr + rr);
            float hh = ftanh(xh + r * rh);
            hout[(size_t)b * RNND + col] =
                z * hin[(size_t)b * RNND + col] + (1.f - z) * hh;
        }
    }
}

// ---------------- P2: q / hpart partials. 64 tasks = which(2) x as(8) x ks(4) ----------------
// Each W2/outW element read exactly once per step.
__device__ void task_qp(int id, const float* W2, const float* outW,
                        const float* hnew, float* qpart, float* hpp, float* sm) {
    int which = id >> 5, r = id & 31, as = r >> 2, ks = r & 3;
    const float* W = which ? outW : W2;   // outW rows [0,512) = h part
    float* outp = which ? hpp : qpart;
    int tid = threadIdx.x;
    for (int it = 0; it < 8; ++it) {
        int lin = it * 512 + tid;
        int k = lin & 127, bb2 = lin >> 7;
        sm[k * 33 + bb2] = hnew[(size_t)bb2 * RNND + ks * 128 + k];
    }
    __syncthreads();
    int b = tid >> 4, cq = tid & 15;
    int col0 = as * 64 + cq * 4;
    float4 a0 = {0, 0, 0, 0};
#pragma unroll 4
    for (int k = 0; k < 128; ++k) {
        float s = sm[k * 33 + b];
        fma4(a0, *(const float4*)&W[(size_t)(ks * 128 + k) * 512 + col0], s);
    }
    *(float4*)&outp[((size_t)ks * BB + b) * 512 + col0] = a0;
}

// ---------------- P3: partial scores. 256 tasks = b(32) x as(8) ----------------
__device__ void task_psc(int id, const float* qpart, const float* V,
                         const float* fp, float* psc, float* sq, float* sV) {
    int b = id >> 3, as = id & 7;
    int tid = threadIdx.x;
    if (tid < 64) {
        int col = as * 64 + tid;
        sq[tid] = qpart[((size_t)0 * BB + b) * 512 + col] +
                  qpart[((size_t)1 * BB + b) * 512 + col] +
                  qpart[((size_t)2 * BB + b) * 512 + col] +
                  qpart[((size_t)3 * BB + b) * 512 + col];
        sV[tid] = V[col];
    }
    __syncthreads();
    int lane = tid & 63, wv = tid >> 6;
    float qv = sq[lane], vv = sV[lane];
    for (int l = wv; l < LL; l += 8) {
        float d = ftanh(fp[((size_t)b * LL + l) * ATTD + as * 64 + lane] + qv) * vv;
#pragma unroll
        for (int o = 32; o > 0; o >>= 1) d += __shfl_xor(d, o);
        if (lane == 0) psc[((size_t)as * BB + b) * LL + l] = d;
    }
}

// ---------------- P4: softmax + outpre + lo -> los[t+1]. 256 tasks = b(32) x jq(8) ----------------
__device__ void task_out(int id, int t, const float* psc, const float* G,
                         const float* hpp, float* los, float* se, float* sred) {
    int b = id >> 3, jq = id & 7;
    int tid = threadIdx.x;
    if (tid < LL) {
        float s = 0.f;
#pragma unroll
        for (int as = 0; as < 8; ++as) s += psc[((size_t)as * BB + b) * LL + tid];
        se[tid] = __expf(s);  // |score| <= sum|V| ~ 20, fp32-safe
    }
    __syncthreads();
    sred[tid] = (tid < LL) ? se[tid] : 0.f;
    __syncthreads();
#pragma unroll
    for (int s = 256; s > 0; s >>= 1) {
        if (tid < s) sred[tid] += sred[tid + s];
        __syncthreads();
    }
    float inv = 1.f / sred[0];
    __syncthreads();
    // gdot: threads (j 64 x lq 8), 50 l each
    int j = tid & 63, lq = tid >> 6;
    float acc = 0.f;
    int l0 = lq * 50;
    for (int l = l0; l < l0 + 50; ++l)
        acc += se[l] * G[((size_t)b * LL + l) * RNND + jq * 64 + j];
    sred[lq * 64 + j] = acc;
    __syncthreads();
    if (tid < 64) {
        float g = 0.f;
#pragma unroll
        for (int q2 = 0; q2 < 8; ++q2) g += sred[q2 * 64 + tid];
        int col = jq * 64 + tid;
        float hps = hpp[((size_t)0 * BB + b) * 512 + col] +
                    hpp[((size_t)1 * BB + b) * 512 + col] +
                    hpp[((size_t)2 * BB + b) * 512 + col] +
                    hpp[((size_t)3 * BB + b) * 512 + col];
        los[((size_t)(t + 1) * BB + b) * RNND + col] = ftanh(hps + inv * g);
    }
}

// ---------------- persistent kernel: 150 steps x 4 phases ----------------
__global__ void __launch_bounds__(TPB) decoder_persist(
    const float* __restrict__ emb, const int* __restrict__ formula,
    const float* __restrict__ Wk, const float* __restrict__ Wr,
    const float* __restrict__ gruB, const float* __restrict__ W2,
    const float* __restrict__ outW, const float* __restrict__ V,
    const float* __restrict__ fp, const float* __restrict__ G,
    float* h0, float* h1, float* qpart, float* hpp, float* psc,
    float* los, unsigned* ctr) {
    __shared__ float sm[128 * 33];   // 16.9KB staging (P1/P2)
    __shared__ float sq[64], sV[64];
    __shared__ float se[LL];
    __shared__ float sred[TPB];
    __shared__ int stok[BB];
    int bid = blockIdx.x;
    int ph = 0;
    for (int t = 0; t < TT; ++t) {
        float* hin = (t & 1) ? h1 : h0;
        float* hout = (t & 1) ? h0 : h1;
        if (bid < 64)
            task_gru(bid, t, emb, formula, Wk, Wr, gruB, hin,
                     los + (size_t)t * BB * RNND, hout, sm, stok);
        gridbar(ctr, ++ph);
        if (bid < 64) task_qp(bid, W2, outW, hout, qpart, hpp, sm);
        gridbar(ctr, ++ph);
        task_psc(bid, qpart, V, fp, psc, sq, sV);
        gridbar(ctr, ++ph);
        task_out(bid, t, psc, G, hpp, los, se, sred);
        gridbar(ctr, ++ph);
    }
}

// ---------------- final: logits = los[1..150] @ projW ----------------
__global__ void __launch_bounds__(256) k_final(
    const float* __restrict__ los, const float* __restrict__ Wp,
    float* __restrict__ out) {
    __shared__ float sa[64 * 68];
    __shared__ unsigned srow[64];
    int mt = blockIdx.x / 40, vt = blockIdx.x % 40;
    int r0 = mt * 64;
    int tid = threadIdx.x;
    if (tid < 64) {
        int r = r0 + tid;
        int bb = r / TT, t = r % TT;
        srow[tid] = (unsigned)(((size_t)(t + 1) * BB + bb) * RNND);
    }
    int aq = tid & 31, blg = tid >> 5;
    int v = vt * 128 + aq * 4;
    bool vok = v < VOCABD;
    float4 acc[8] = {};
    __syncthreads();
    for (int kc = 0; kc < RNND; kc += 64) {
        for (int it = 0; it < 16; ++it) {
            int lin = it * 256 + tid;
            int k = lin & 63, rl = lin >> 6;
            sa[k * 68 + rl] = los[srow[rl] + kc + k];
        }
        __syncthreads();
        if (vok) {
#pragma unroll 4
            for (int k = 0; k < 64; ++k) {
                float4 w = *(const float4*)&Wp[(size_t)(kc + k) * VOCABD + v];
                float4 s0 = *(const float4*)&sa[k * 68 + blg * 8];
                float4 s1 = *(const float4*)&sa[k * 68 + blg * 8 + 4];
                fma4(acc[0], w, s0.x); fma4(acc[1], w, s0.y);
                fma4(acc[2], w, s0.z); fma4(acc[3], w, s0.w);
                fma4(acc[4], w, s1.x); fma4(acc[5], w, s1.y);
                fma4(acc[6], w, s1.z); fma4(acc[7], w, s1.w);
            }
        }
        __syncthreads();
    }
    if (vok) {
#pragma unroll
        for (int i = 0; i < 8; ++i)
            *(float4*)&out[(size_t)(r0 + blg * 8 + i) * VOCABD + v] = acc[i];
    }
}

extern "C" void kernel_launch(void* const* d_in, const int* in_sizes, int n_in,
                              void* d_out, int out_size, void* d_ws, size_t ws_size,
                              hipStream_t stream) {
    const float* features  = (const float*)d_in[0];
    const float* initstate = (const float*)d_in[1];
    const float* emb       = (const float*)d_in[2];
    const float* gruK      = (const float*)d_in[3];
    const float* gruR      = (const float*)d_in[4];
    const float* gruB      = (const float*)d_in[5];
    const float* W1        = (const float*)d_in[6];
    const float* W2        = (const float*)d_in[7];
    const float* V         = (const float*)d_in[8];
    const float* outW      = (const float*)d_in[9];
    const float* projW     = (const float*)d_in[10];
    const int*   formula   = (const int*)d_in[11];
    float* logits = (float*)d_out;

    float* ws = (float*)d_ws;
    unsigned* ctr = (unsigned*)ws;                    // 32 u32
    float* h0    = ws + 32;                           // 16,384
    float* h1    = h0 + (size_t)BB * RNND;            // 16,384
    float* qpart = h1 + (size_t)BB * RNND;            // 65,536
    float* hpp   = qpart + (size_t)4 * BB * 512;      // 65,536
    float* psc   = hpp + (size_t)4 * BB * 512;        // 102,400
    float* los   = psc + (size_t)8 * BB * LL;         // 151 slots: 2,473,984
    float* fp    = los + (size_t)(TT + 1) * BB * RNND;// 6,553,600
    float* G     = fp + (size_t)BB * LL * ATTD;       // 6,553,600

    hipMemsetAsync(ctr, 0, NCTR * sizeof(unsigned), stream);
    hipMemsetAsync(los, 0, (size_t)BB * RNND * sizeof(float), stream);
    hipMemcpyAsync(h0, initstate, (size_t)BB * RNND * sizeof(float),
                   hipMemcpyDeviceToDevice, stream);

    k_proj512<<<800, 256, 0, stream>>>(features, W1, fp);
    k_proj512<<<800, 256, 0, stream>>>(features, outW + (size_t)512 * RNND, G);

    decoder_persist<<<GRID, TPB, 0, stream>>>(
        emb, formula, gruK, gruR, gruB, W2, outW, V, fp, G,
        h0, h1, qpart, hpp, psc, los, ctr);

    k_final<<<75 * 40, 256, 0, stream>>>(los, projW, logits);
}

// Round 9
// 13399.454 us; speedup vs baseline: 5.2668x; 5.2668x over previous
//
#include <hip/hip_runtime.h>

#define BB 32
#define TT 150
#define LL 400
#define FEATD 512
#define RNND 512
#define ATTD 512
#define EMBD 256
#define VOCABD 5000
#define G3 1536

__device__ __forceinline__ float fsigmoid(float x) { return 1.f / (1.f + __expf(-x)); }
__device__ __forceinline__ float ftanh(float x) {
    x = fminf(15.f, fmaxf(-15.f, x));
    float e = __expf(2.f * x);
    return 1.f - 2.f / (e + 1.f);
}
__device__ __forceinline__ void fma4(float4& a, const float4 w, const float s) {
    a.x += w.x * s; a.y += w.y * s; a.z += w.z * s; a.w += w.w * s;
}

// ---------------- one-time GEMM: [B*L,512] @ [512,512] (fp and G) ----------------
__global__ void __launch_bounds__(256) k_proj512(const float* __restrict__ features,
                                                 const float* __restrict__ W,
                                                 float* __restrict__ outb) {
    __shared__ float sa[64 * 68];
    int blt = blockIdx.x >> 2, at = blockIdx.x & 3;
    int bl0 = blt * 64;
    int tid = threadIdx.x;
    int aq = tid & 31, blg = tid >> 5;
    float4 acc[8] = {};
    for (int kc = 0; kc < FEATD; kc += 64) {
        __syncthreads();
        for (int it = 0; it < 16; ++it) {
            int lin = it * 256 + tid;
            int k = lin & 63, bl = lin >> 6;
            sa[k * 68 + bl] = features[((size_t)bl0 + bl) * FEATD + kc + k];
        }
        __syncthreads();
#pragma unroll 4
        for (int k = 0; k < 64; ++k) {
            float4 w = *(const float4*)&W[(size_t)(kc + k) * 512 + at * 128 + aq * 4];
            float4 s0 = *(const float4*)&sa[k * 68 + blg * 8];
            float4 s1 = *(const float4*)&sa[k * 68 + blg * 8 + 4];
            fma4(acc[0], w, s0.x); fma4(acc[1], w, s0.y);
            fma4(acc[2], w, s0.z); fma4(acc[3], w, s0.w);
            fma4(acc[4], w, s1.x); fma4(acc[5], w, s1.y);
            fma4(acc[6], w, s1.z); fma4(acc[7], w, s1.w);
        }
    }
#pragma unroll
    for (int i = 0; i < 8; ++i)
        *(float4*)&outb[((size_t)bl0 + blg * 8 + i) * 512 + at * 128 + aq * 4] = acc[i];
}

// ---------------- K1: gate GEMM partials + inline lo(t-1). 120 blocks ----------------
// mx: [emb(tok) | lo(t-1)] (K=768) @ Wk -> mxp[3], mh: h(t-1) @ Wr -> mhp[2].
// lo(t-1) = tanh(hpart + gdot/esum) reconstructed from step t-1 partials during
// staging (t=0: zeros). jt==0 lo-blocks also write los[t] for the final GEMM.
__global__ void __launch_bounds__(256) k_gates(
    const float* __restrict__ emb, const int* __restrict__ formula,
    const float* __restrict__ Wk, const float* __restrict__ Wr,
    const float* __restrict__ hin, const float* __restrict__ qhp,
    const float* __restrict__ gdotp, const float* __restrict__ esump,
    float* __restrict__ mxp, float* __restrict__ mhp,
    float* __restrict__ los, int t) {
    __shared__ float sm[256 * 36];
    __shared__ float sinv[BB];
    __shared__ int stok[BB];
    int id = blockIdx.x, tid = threadIdx.x;
    bool isMX = id < 72;
    int jt, ks; const float* W; float* ob;
    if (isMX) { jt = id / 3; ks = id % 3; W = Wk; ob = mxp; }
    else { int r = id - 72; jt = r >> 1; ks = r & 1; W = Wr; ob = mhp; }
    int k0 = ks * 256;
    if (isMX && ks == 0 && tid < BB) stok[tid] = formula[tid * TT + t];
    if (isMX && ks > 0 && t > 0 && tid < BB) {
        float s = 0.f;
#pragma unroll
        for (int ls = 0; ls < 8; ++ls) s += esump[ls * BB + tid];
        sinv[tid] = 1.f / s;
    }
    __syncthreads();
    for (int it = 0; it < 32; ++it) {
        int lin = it * 256 + tid;
        int k = lin & 255, b = lin >> 8;
        float v;
        if (!isMX) {
            v = hin[(size_t)b * RNND + k0 + k];
        } else if (ks == 0) {
            v = emb[(size_t)stok[b] * EMBD + k];
        } else {
            int kr = (ks - 1) * 256 + k;
            if (t == 0) {
                v = 0.f;  // lo(-1) = tanh(0) with zero out-state
            } else {
                float hp = qhp[((size_t)0 * BB + b) * 1024 + 512 + kr] +
                           qhp[((size_t)1 * BB + b) * 1024 + 512 + kr] +
                           qhp[((size_t)2 * BB + b) * 1024 + 512 + kr] +
                           qhp[((size_t)3 * BB + b) * 1024 + 512 + kr];
                float g = 0.f;
#pragma unroll
                for (int ls = 0; ls < 8; ++ls)
                    g += gdotp[((size_t)ls * BB + b) * 512 + kr];
                v = ftanh(hp + sinv[b] * g);
            }
            if (jt == 0) los[((size_t)t * BB + b) * RNND + kr] = v;  // slot t = lo(t-1)
        }
        sm[k * 36 + b] = v;
    }
    __syncthreads();
    int jq = tid & 15, bg = tid >> 4;
    int j = jt * 64 + jq * 4;
    float4 a0 = {0, 0, 0, 0}, a1 = {0, 0, 0, 0};
#pragma unroll 4
    for (int k = 0; k < 256; ++k) {
        float4 w = *(const float4*)&W[(size_t)(k0 + k) * G3 + j];
        float2 s = *(const float2*)&sm[k * 36 + bg * 2];
        fma4(a0, w, s.x);
        fma4(a1, w, s.y);
    }
    int b = bg * 2;
    *(float4*)&ob[((size_t)ks * BB + b) * G3 + j] = a0;
    *(float4*)&ob[((size_t)ks * BB + b + 1) * G3 + j] = a1;
}

// ---------------- K2: combine -> h(t) + q|hpart GEMM partials. 64 blocks ----------------
// blocks = tile(16: cols 0-511 q via W2, 512-1023 hpart via outW rows 0-511) x ks(4).
// Staging recomputes GRU combine for the 128-k slice (dup x16 tiles, cheap reads);
// tile==0 writes h. Weights read exactly once per step.
__global__ void __launch_bounds__(256) k_qh(
    const float* __restrict__ mxp, const float* __restrict__ mhp,
    const float* __restrict__ gruB, const float* __restrict__ W2,
    const float* __restrict__ outW, const float* __restrict__ hin,
    float* __restrict__ hout, float* __restrict__ qhp) {
    __shared__ float sm[128 * 34];
    int tile = blockIdx.x >> 2, ks = blockIdx.x & 3;
    int tid = threadIdx.x;
    int k0 = ks * 128;
    for (int it = 0; it < 16; ++it) {
        int lin = it * 256 + tid;
        int k = lin & 127, b = lin >> 7;
        int j = k0 + k;
        size_t m0 = ((size_t)0 * BB + b) * G3, m1 = ((size_t)1 * BB + b) * G3,
               m2 = ((size_t)2 * BB + b) * G3;
        float xz = gruB[j] + mxp[m0 + j] + mxp[m1 + j] + mxp[m2 + j];
        float xr = gruB[512 + j] + mxp[m0 + 512 + j] + mxp[m1 + 512 + j] + mxp[m2 + 512 + j];
        float xh = gruB[1024 + j] + mxp[m0 + 1024 + j] + mxp[m1 + 1024 + j] + mxp[m2 + 1024 + j];
        float rz = gruB[G3 + j] + mhp[m0 + j] + mhp[m1 + j];
        float rr = gruB[G3 + 512 + j] + mhp[m0 + 512 + j] + mhp[m1 + 512 + j];
        float rh = gruB[G3 + 1024 + j] + mhp[m0 + 1024 + j] + mhp[m1 + 1024 + j];
        float z = fsigmoid(xz + rz), r = fsigmoid(xr + rr);
        float hh = ftanh(xh + r * rh);
        float hn = z * hin[(size_t)b * RNND + j] + (1.f - z) * hh;
        sm[k * 34 + b] = hn;
        if (tile == 0) hout[(size_t)b * RNND + j] = hn;
    }
    __syncthreads();
    const float* W = (tile < 8) ? W2 : outW;  // outW rows [0,512) = h part
    int cb = (tile & 7) * 64;
    int jq = tid & 15, bg = tid >> 4;
    int j = cb + jq * 4;
    float4 a0 = {0, 0, 0, 0}, a1 = {0, 0, 0, 0};
#pragma unroll 4
    for (int k = 0; k < 128; ++k) {
        float4 w = *(const float4*)&W[(size_t)(k0 + k) * 512 + j];
        float2 s = *(const float2*)&sm[k * 34 + bg * 2];
        fma4(a0, w, s.x);
        fma4(a1, w, s.y);
    }
    int b = bg * 2;
    int outcol = tile * 64 + jq * 4;  // 0..1023
    *(float4*)&qhp[((size_t)ks * BB + b) * 1024 + outcol] = a0;
    *(float4*)&qhp[((size_t)ks * BB + b + 1) * 1024 + outcol] = a1;
}

// ---------------- K3: scores + exp + esump + unnormalized gdot. 256 blocks = b x ls(8) ----------------
__global__ void __launch_bounds__(256) k_attn(
    const float* __restrict__ qhp, const float* __restrict__ V,
    const float* __restrict__ fp, const float* __restrict__ G,
    float* __restrict__ gdotp, float* __restrict__ esump) {
    __shared__ float sq[ATTD];
    __shared__ float sV[ATTD];
    __shared__ float se[64];
    int b = blockIdx.x >> 3, ls = blockIdx.x & 7, l0 = ls * 50;
    int tid = threadIdx.x;
#pragma unroll
    for (int cc = 0; cc < 2; ++cc) {
        int c = tid + cc * 256;
        sq[c] = qhp[((size_t)0 * BB + b) * 1024 + c] +
                qhp[((size_t)1 * BB + b) * 1024 + c] +
                qhp[((size_t)2 * BB + b) * 1024 + c] +
                qhp[((size_t)3 * BB + b) * 1024 + c];
        sV[c] = V[c];
    }
    if (tid >= 50 && tid < 64) se[tid] = 0.f;
    __syncthreads();
    int lane = tid & 63, wv = tid >> 6;
    float4 q0 = ((const float4*)sq)[lane], q1 = ((const float4*)sq)[64 + lane];
    float4 v0 = ((const float4*)sV)[lane], v1 = ((const float4*)sV)[64 + lane];
    for (int ll = wv; ll < 50; ll += 4) {
        const float4* row = (const float4*)(fp + ((size_t)b * LL + l0 + ll) * ATTD);
        float4 f0 = row[lane], f1 = row[64 + lane];
        float d = ftanh(f0.x + q0.x) * v0.x + ftanh(f0.y + q0.y) * v0.y +
                  ftanh(f0.z + q0.z) * v0.z + ftanh(f0.w + q0.w) * v0.w +
                  ftanh(f1.x + q1.x) * v1.x + ftanh(f1.y + q1.y) * v1.y +
                  ftanh(f1.z + q1.z) * v1.z + ftanh(f1.w + q1.w) * v1.w;
#pragma unroll
        for (int o = 32; o > 0; o >>= 1) d += __shfl_xor(d, o);
        if (lane == 0) se[ll] = __expf(d);  // |score| <= sum|V| ~ 20, fp32-safe
    }
    __syncthreads();
    if (tid < 64) {
        float x = se[tid];
#pragma unroll
        for (int o = 32; o > 0; o >>= 1) x += __shfl_xor(x, o);
        if (tid == 0) esump[ls * BB + b] = x;
    }
    // unnormalized gdot partials over this l-chunk
    float a0 = 0.f, a1 = 0.f;
#pragma unroll 2
    for (int l = 0; l < 50; ++l) {
        float e = se[l];
        const float* gr = G + ((size_t)b * LL + l0 + l) * RNND;
        a0 += e * gr[tid];
        a1 += e * gr[tid + 256];
    }
    gdotp[((size_t)ls * BB + b) * 512 + tid] = a0;
    gdotp[((size_t)ls * BB + b) * 512 + tid + 256] = a1;
}

// ---------------- tail: lo(149) -> los slot 150 ----------------
__global__ void __launch_bounds__(256) k_lo_tail(
    const float* __restrict__ qhp, const float* __restrict__ gdotp,
    const float* __restrict__ esump, float* __restrict__ los) {
    __shared__ float sinvs;
    int b = blockIdx.x, tid = threadIdx.x;
    if (tid == 0) {
        float s = 0.f;
#pragma unroll
        for (int ls = 0; ls < 8; ++ls) s += esump[ls * BB + b];
        sinvs = 1.f / s;
    }
    __syncthreads();
#pragma unroll
    for (int jj = 0; jj < 2; ++jj) {
        int j = tid + jj * 256;
        float hp = qhp[((size_t)0 * BB + b) * 1024 + 512 + j] +
                   qhp[((size_t)1 * BB + b) * 1024 + 512 + j] +
                   qhp[((size_t)2 * BB + b) * 1024 + 512 + j] +
                   qhp[((size_t)3 * BB + b) * 1024 + 512 + j];
        float g = 0.f;
#pragma unroll
        for (int ls = 0; ls < 8; ++ls) g += gdotp[((size_t)ls * BB + b) * 512 + j];
        los[((size_t)TT * BB + b) * RNND + j] = ftanh(hp + sinvs * g);
    }
}

// ---------------- final: logits = los[1..150] @ projW ----------------
// row r = b*150+t -> los slot t+1. 75 row-tiles x 40 v-tiles.
__global__ void __launch_bounds__(256) k_final(
    const float* __restrict__ los, const float* __restrict__ Wp,
    float* __restrict__ out) {
    __shared__ float sa[64 * 68];
    __shared__ unsigned srow[64];
    int mt = blockIdx.x / 40, vt = blockIdx.x % 40;
    int r0 = mt * 64;
    int tid = threadIdx.x;
    if (tid < 64) {
        int r = r0 + tid;
        int bb = r / TT, t = r % TT;
        srow[tid] = (unsigned)(((size_t)(t + 1) * BB + bb) * RNND);
    }
    int aq = tid & 31, blg = tid >> 5;
    int v = vt * 128 + aq * 4;
    bool vok = v < VOCABD;
    float4 acc[8] = {};
    __syncthreads();
    for (int kc = 0; kc < RNND; kc += 64) {
        for (int it = 0; it < 16; ++it) {
            int lin = it * 256 + tid;
            int k = lin & 63, rl = lin >> 6;
            sa[k * 68 + rl] = los[srow[rl] + kc + k];
        }
        __syncthreads();
        if (vok) {
#pragma unroll 4
            for (int k = 0; k < 64; ++k) {
                float4 w = *(const float4*)&Wp[(size_t)(kc + k) * VOCABD + v];
                float4 s0 = *(const float4*)&sa[k * 68 + blg * 8];
                float4 s1 = *(const float4*)&sa[k * 68 + blg * 8 + 4];
                fma4(acc[0], w, s0.x); fma4(acc[1], w, s0.y);
                fma4(acc[2], w, s0.z); fma4(acc[3], w, s0.w);
                fma4(acc[4], w, s1.x); fma4(acc[5], w, s1.y);
                fma4(acc[6], w, s1.z); fma4(acc[7], w, s1.w);
            }
        }
        __syncthreads();
    }
    if (vok) {
#pragma unroll
        for (int i = 0; i < 8; ++i)
            *(float4*)&out[(size_t)(r0 + blg * 8 + i) * VOCABD + v] = acc[i];
    }
}

extern "C" void kernel_launch(void* const* d_in, const int* in_sizes, int n_in,
                              void* d_out, int out_size, void* d_ws, size_t ws_size,
                              hipStream_t stream) {
    const float* features  = (const float*)d_in[0];
    const float* initstate = (const float*)d_in[1];
    const float* emb       = (const float*)d_in[2];
    const float* gruK      = (const float*)d_in[3];
    const float* gruR      = (const float*)d_in[4];
    const float* gruB      = (const float*)d_in[5];
    const float* W1        = (const float*)d_in[6];
    const float* W2        = (const float*)d_in[7];
    const float* V         = (const float*)d_in[8];
    const float* outW      = (const float*)d_in[9];
    const float* projW     = (const float*)d_in[10];
    const int*   formula   = (const int*)d_in[11];
    float* logits = (float*)d_out;

    float* ws = (float*)d_ws;
    float* h0    = ws;                                  // 16,384
    float* h1    = h0 + (size_t)BB * RNND;              // 16,384
    float* mxp   = h1 + (size_t)BB * RNND;              // 147,456
    float* mhp   = mxp + (size_t)3 * BB * G3;           // 98,304
    float* qhp   = mhp + (size_t)2 * BB * G3;           // 131,072
    float* gdotp = qhp + (size_t)4 * BB * 1024;         // 131,072
    float* esump = gdotp + (size_t)8 * BB * RNND;       // 256
    float* los   = esump + 8 * BB;                      // 151 slots: 2,473,984
    float* fp    = los + (size_t)(TT + 1) * BB * RNND;  // 6,553,600
    float* G     = fp + (size_t)BB * LL * ATTD;         // 6,553,600

    hipMemcpyAsync(h0, initstate, (size_t)BB * RNND * sizeof(float),
                   hipMemcpyDeviceToDevice, stream);

    k_proj512<<<800, 256, 0, stream>>>(features, W1, fp);
    k_proj512<<<800, 256, 0, stream>>>(features, outW + (size_t)512 * RNND, G);

    float* hin = h0;
    float* hout = h1;
    for (int t = 0; t < TT; ++t) {
        k_gates<<<120, 256, 0, stream>>>(emb, formula, gruK, gruR, hin,
                                         qhp, gdotp, esump, mxp, mhp, los, t);
        k_qh<<<64, 256, 0, stream>>>(mxp, mhp, gruB, W2, outW, hin, hout, qhp);
        k_attn<<<256, 256, 0, stream>>>(qhp, V, fp, G, gdotp, esump);
        float* tmp = hin; hin = hout; hout = tmp;
    }
    k_lo_tail<<<BB, 256, 0, stream>>>(qhp, gdotp, esump, los);
    k_final<<<75 * 40, 256, 0, stream>>>(los, projW, logits);
}